// Round 1
// 470.523 us; speedup vs baseline: 1.0226x; 1.0226x over previous
//
#include <hip/hip_runtime.h>
#include <hip/hip_bf16.h>
#include <float.h>

// SplitNN v4: counted-vmcnt 3-deep async pipeline (no vmcnt(0) drains in the
// steady loop), noise via per-wave register double-buffer, all-wave redundant
// head MFMA with direct register stores (uniform per-wave vmem counts so the
// waitcnt arithmetic is exact). B=262144, F=160, H=128, C=10, fp32 in/out.

typedef __bf16 bf16x8 __attribute__((ext_vector_type(8)));
typedef __bf16 bf16x4 __attribute__((ext_vector_type(4)));
typedef float  f32x4  __attribute__((ext_vector_type(4)));

#define FDIM 160
#define HDIM 128
#define SROW 132   // sbuf bf16 stride: 264B rows -> <=4-way LDS aliasing on head reads

#define GL2LDS(g, l) __builtin_amdgcn_global_load_lds( \
    (const __attribute__((address_space(1))) unsigned int*)(g), \
    (__attribute__((address_space(3))) unsigned int*)(l), 16, 0, 0)

__global__ void k0_prep(const float* __restrict__ W1, const float* __restrict__ W2,
                        unsigned int* __restrict__ mmx,
                        __bf16* __restrict__ w1t, __bf16* __restrict__ w2t) {
    int tid = blockIdx.x * 256 + threadIdx.x;
    if (tid == 0) { mmx[0] = 0x7F7FFFFFu; /* FLT_MAX */ mmx[1] = 0u; }
    for (int idx = tid; idx < FDIM * HDIM; idx += gridDim.x * 256) {
        int k = idx >> 7, n = idx & 127;      // W[k][n] row-major
        w1t[n * FDIM + k] = (__bf16)W1[idx];
        w2t[n * FDIM + k] = (__bf16)W2[idx];
    }
}

__device__ __forceinline__ bf16x8 pack8(f32x4 lo, f32x4 hi) {
    bf16x8 a;
    a[0] = (__bf16)lo[0]; a[1] = (__bf16)lo[1]; a[2] = (__bf16)lo[2]; a[3] = (__bf16)lo[3];
    a[4] = (__bf16)hi[0]; a[5] = (__bf16)hi[1]; a[6] = (__bf16)hi[2]; a[7] = (__bf16)hi[3];
    return a;
}

// K1: global min/max of row-L1(x1@W1+b1). 3-deep staging, counted vmcnt.
// Per-wave stage batch: wv0/wv1 = 3 chunks, wv2/wv3 = 2 chunks. Stage(i+2) is
// issued at the END of iter i, so at the top of iter i only stage(i+1) is
// newer than stage(i) -> wait vmcnt(S) with S = own batch size.
__global__ __launch_bounds__(256, 4) void k1_sens(
    const float* __restrict__ x1, const float* __restrict__ b1,
    const __bf16* __restrict__ w1t, unsigned int* __restrict__ mmx, int B)
{
    __shared__ __align__(16) char stg[3][10 * 1024];
    __shared__ float nbuf[2][4][16];                   // [parity][wave][batch-row]

    const int lane = threadIdx.x & 63;
    const int wv   = threadIdx.x >> 6;
    const int m    = lane & 15;
    const int q    = lane >> 4;

    bf16x8 wf[2][5];
    f32x4  bv[2];
    #pragma unroll
    for (int cc = 0; cc < 2; ++cc) {
        const int ct = 2 * wv + cc;
        bv[cc] = *(const f32x4*)&b1[ct * 16 + q * 4];
        #pragma unroll
        for (int ks = 0; ks < 5; ++ks)
            wf[cc][ks] = *(const bf16x8*)(w1t + (ct * 16 + m) * FDIM + ks * 32 + q * 8);
    }

    const int nslab = B >> 4;
    const int G = gridDim.x;

    auto stage = [&](int buf, int slab) {
        if (slab >= nslab) slab = 0;                   // tail clamp: keep counts uniform
        const float* rowp = x1 + (size_t)((slab << 4) + m) * FDIM + q * 8;
        if (wv < 2) {
            #pragma unroll
            for (int j = 0; j < 3; ++j) {
                const int c = wv * 3 + j;
                GL2LDS(rowp + (c >> 1) * 32 + (c & 1) * 4, &stg[buf][c * 1024]);
            }
        } else {
            #pragma unroll
            for (int j = 0; j < 2; ++j) {
                const int c = 6 + (wv - 2) * 2 + j;
                GL2LDS(rowp + (c >> 1) * 32 + (c & 1) * 4, &stg[buf][c * 1024]);
            }
        }
    };

    float wmin = FLT_MAX, wmax = 0.0f;
    int it = blockIdx.x, iter = 0, cur = 0;
    if (it < nslab) {
        stage(0, it);
        stage(1, it + G);
        for (; it < nslab; it += G) {
            // publish: my stage(i) chunks done (counted), my nbuf ds_write drained.
            if (wv < 2) asm volatile("s_waitcnt vmcnt(3) lgkmcnt(0)\n\ts_barrier" ::: "memory");
            else        asm volatile("s_waitcnt vmcnt(2) lgkmcnt(0)\n\ts_barrier" ::: "memory");
            if (iter > 0 && wv == 0 && lane < 16) {
                const int pb = (iter - 1) & 1;
                float nrm = nbuf[pb][0][m] + nbuf[pb][1][m] + nbuf[pb][2][m] + nbuf[pb][3][m];
                wmin = fminf(wmin, nrm); wmax = fmaxf(wmax, nrm);
            }
            f32x4 acc[2] = { bv[0], bv[1] };
            #pragma unroll
            for (int ks = 0; ks < 5; ++ks) {
                f32x4 lo = *(const f32x4*)&stg[cur][(2 * ks) * 1024 + lane * 16];
                f32x4 hi = *(const f32x4*)&stg[cur][(2 * ks + 1) * 1024 + lane * 16];
                bf16x8 a = pack8(lo, hi);
                acc[0] = __builtin_amdgcn_mfma_f32_16x16x32_bf16(wf[0][ks], a, acc[0], 0, 0, 0);
                acc[1] = __builtin_amdgcn_mfma_f32_16x16x32_bf16(wf[1][ks], a, acc[1], 0, 0, 0);
            }
            float part = 0.0f;
            #pragma unroll
            for (int cc = 0; cc < 2; ++cc)
                #pragma unroll
                for (int reg = 0; reg < 4; ++reg) part += fabsf(acc[cc][reg]);
            part += __shfl_xor(part, 16, 64);
            part += __shfl_xor(part, 32, 64);
            if (lane < 16) nbuf[iter & 1][wv][m] = part;
            { int nb = cur + 2; if (nb >= 3) nb -= 3; stage(nb, it + 2 * G); }
            cur = (cur == 2) ? 0 : cur + 1;
            ++iter;
        }
    }
    __syncthreads();
    if (iter > 0 && wv == 0 && lane < 16) {
        const int pb = (iter - 1) & 1;
        float nrm = nbuf[pb][0][m] + nbuf[pb][1][m] + nbuf[pb][2][m] + nbuf[pb][3][m];
        wmin = fminf(wmin, nrm); wmax = fmaxf(wmax, nrm);
    }
    if (wv == 0) {
        #pragma unroll
        for (int off = 1; off < 16; off <<= 1) {
            wmin = fminf(wmin, __shfl_xor(wmin, off, 64));
            wmax = fmaxf(wmax, __shfl_xor(wmax, off, 64));
        }
        if (lane == 0) {
            atomicMin(&mmx[0], __float_as_uint(wmin));  // norms >= 0: uint order == float order
            atomicMax(&mmx[1], __float_as_uint(wmax));
        }
    }
}

// K2: 3-deep stage of x1+x2 (20 chunks, 5/wave uniform), noise in per-wave
// register double-buffer, all-wave redundant head, direct register stores.
// Per-wave vmem issue order per iter: [nz 2][stores 4][stage 5] = 11 ops.
// Top-of-iter wait needs stage(i) (last ops of iter i-2) done; everything
// after it = nz(i) + stores(i-1) + stage(i+1) = 11 -> vmcnt(11).
// Peeled iter 0: prologue issued [nz(0) 2][stage(0) 5][stage(1) 5]; only
// stage(1) is guaranteed after stage(0) -> vmcnt(5).
__global__ __launch_bounds__(256, 2) void k2_main(
    const float* __restrict__ x1, const float* __restrict__ x2,
    const float* __restrict__ b1, const float* __restrict__ b2,
    const float* __restrict__ Ws, const float* __restrict__ bs,
    const float* __restrict__ noise, const float* __restrict__ rru,
    const __bf16* __restrict__ w1t, const __bf16* __restrict__ w2t,
    const unsigned int* __restrict__ mmx, float* __restrict__ out, int B)
{
    __shared__ __align__(16) char   stg[3][20 * 1024];  // chunks: 0-9 x1, 10-19 x2
    __shared__ __align__(16) __bf16 sbuf[16 * SROW];    // s tile [batch][h]

    const int lane = threadIdx.x & 63;
    const int wv   = threadIdx.x >> 6;
    const int m    = lane & 15;
    const int q    = lane >> 4;

    const float noise_mul = (__uint_as_float(mmx[1]) - __uint_as_float(mmx[0])) * 7.5f;

    bf16x8 wf1[2][5], wf2[2][5];
    f32x4  bv1[2], bv2[2];
    unsigned rmask = 0;
    #pragma unroll
    for (int cc = 0; cc < 2; ++cc) {
        const int ct = 2 * wv + cc;
        bv1[cc] = *(const f32x4*)&b1[ct * 16 + q * 4];
        bv2[cc] = *(const f32x4*)&b2[ct * 16 + q * 4];
        f32x4 r4 = *(const f32x4*)&rru[ct * 16 + q * 4];
        #pragma unroll
        for (int reg = 0; reg < 4; ++reg)
            if (r4[reg] < 0.95f) rmask |= 1u << (cc * 4 + reg);
        #pragma unroll
        for (int ks = 0; ks < 5; ++ks) {
            wf1[cc][ks] = *(const bf16x8*)(w1t + (ct * 16 + m) * FDIM + ks * 32 + q * 8);
            wf2[cc][ks] = *(const bf16x8*)(w2t + (ct * 16 + m) * FDIM + ks * 32 + q * 8);
        }
    }
    bf16x8 wsf[4];
    #pragma unroll
    for (int ks2 = 0; ks2 < 4; ++ks2)
        #pragma unroll
        for (int j = 0; j < 8; ++j) {
            int h = ks2 * 32 + q * 8 + j;
            wsf[ks2][j] = (__bf16)((m < 10) ? Ws[h * 10 + m] : 0.0f);
        }
    const float bsv = (m < 10) ? bs[m] : 0.0f;

    const int nslab = B >> 4;
    const int G = gridDim.x;

    auto stage = [&](int buf, int slab) {
        if (slab >= nslab) slab = 0;                   // tail clamp: keep counts uniform
        const int r0 = slab << 4;
        const float* x1p = x1 + (size_t)(r0 + m) * FDIM + q * 8;
        const float* x2p = x2 + (size_t)(r0 + m) * FDIM + q * 8;
        #pragma unroll
        for (int j = 0; j < 5; ++j) {
            const int c = wv * 5 + j;                  // uniform per wave, 5 each
            const float* g = (c < 10) ? (x1p + (c >> 1) * 32 + (c & 1) * 4)
                                      : (x2p + ((c - 10) >> 1) * 32 + ((c - 10) & 1) * 4);
            GL2LDS(g, &stg[buf][c * 1024]);
        }
    };

#define K2_BODY(VMWS)                                                              \
  {                                                                                \
    asm volatile("s_waitcnt vmcnt(" VMWS ") lgkmcnt(0)\n\ts_barrier" ::: "memory");\
    /* next-iter noise prefetch (clamped; always 2 loads -> uniform vmcnt) */      \
    int nsl_ = it + G; if (nsl_ >= nslab) nsl_ = 0;                                \
    const float* nzp_ = noise + (size_t)((nsl_ << 4) + m) * HDIM + q * 4;          \
    f32x4 nz_nxt0 = *(const f32x4*)(nzp_ + (2 * wv) * 16);                         \
    f32x4 nz_nxt1 = *(const f32x4*)(nzp_ + (2 * wv + 1) * 16);                     \
    f32x4 acc1[2] = { bv1[0], bv1[1] }, acc2[2] = { bv2[0], bv2[1] };              \
    _Pragma("unroll")                                                              \
    for (int ks = 0; ks < 5; ++ks) {                                               \
        f32x4 lo1 = *(const f32x4*)&stg[cur][(2 * ks) * 1024 + lane * 16];         \
        f32x4 hi1 = *(const f32x4*)&stg[cur][(2 * ks + 1) * 1024 + lane * 16];     \
        f32x4 lo2 = *(const f32x4*)&stg[cur][(10 + 2 * ks) * 1024 + lane * 16];    \
        f32x4 hi2 = *(const f32x4*)&stg[cur][(11 + 2 * ks) * 1024 + lane * 16];    \
        bf16x8 a1 = pack8(lo1, hi1), a2 = pack8(lo2, hi2);                         \
        acc1[0] = __builtin_amdgcn_mfma_f32_16x16x32_bf16(wf1[0][ks], a1, acc1[0], 0, 0, 0); \
        acc1[1] = __builtin_amdgcn_mfma_f32_16x16x32_bf16(wf1[1][ks], a1, acc1[1], 0, 0, 0); \
        acc2[0] = __builtin_amdgcn_mfma_f32_16x16x32_bf16(wf2[0][ks], a2, acc2[0], 0, 0, 0); \
        acc2[1] = __builtin_amdgcn_mfma_f32_16x16x32_bf16(wf2[1][ks], a2, acc2[1], 0, 0, 0); \
    }                                                                              \
    _Pragma("unroll")                                                              \
    for (int cc = 0; cc < 2; ++cc) {                                               \
        bf16x4 pk;                                                                 \
        _Pragma("unroll")                                                          \
        for (int reg = 0; reg < 4; ++reg) {                                        \
            float v1 = acc1[cc][reg] + ((cc == 0) ? nz_cur0[reg] : nz_cur1[reg]) * noise_mul; \
            v1 = ((rmask >> (cc * 4 + reg)) & 1u) ? v1 : 0.0f;                     \
            pk[reg] = (__bf16)fminf(v1, acc2[cc][reg]);                            \
        }                                                                          \
        *(bf16x4*)&sbuf[m * SROW + (2 * wv + cc) * 16 + q * 4] = pk;               \
    }                                                                              \
    asm volatile("s_waitcnt lgkmcnt(0)\n\ts_barrier" ::: "memory");                \
    /* head: all waves compute redundantly (matrix pipe is ~6% busy), each     */  \
    /* wave stores its own 4 rows (q==wv) straight from registers.             */  \
    f32x4 d = { bsv, bsv, bsv, bsv };                                              \
    _Pragma("unroll")                                                              \
    for (int ks2 = 0; ks2 < 4; ++ks2) {                                            \
        bf16x8 sf = *(const bf16x8*)&sbuf[m * SROW + ks2 * 32 + q * 8];            \
        d = __builtin_amdgcn_mfma_f32_16x16x32_bf16(sf, wsf[ks2], d, 0, 0, 0);     \
    }                                                                              \
    if (q == wv && m < 10) {                                                       \
        _Pragma("unroll")                                                          \
        for (int reg = 0; reg < 4; ++reg)                                          \
            out[(size_t)(it * 16 + q * 4 + reg) * 10 + m] = d[reg];                \
    }                                                                              \
    { int nb_ = cur + 2; if (nb_ >= 3) nb_ -= 3; stage(nb_, it + 2 * G); }         \
    nz_cur0 = nz_nxt0; nz_cur1 = nz_nxt1;                                          \
  }

    int it = blockIdx.x, cur = 0;
    if (it < nslab) {
        f32x4 nz_cur0, nz_cur1;
        {   // prologue: nz(0) first, then stage(0), stage(1)
            const float* nzp0 = noise + (size_t)((it << 4) + m) * HDIM + q * 4;
            nz_cur0 = *(const f32x4*)(nzp0 + (2 * wv) * 16);
            nz_cur1 = *(const f32x4*)(nzp0 + (2 * wv + 1) * 16);
        }
        stage(0, it);
        stage(1, it + G);
        K2_BODY("5");                                   // iter 0 (peeled wait)
        it += G; cur = 1;
        for (; it < nslab; it += G) {
            K2_BODY("11");                              // steady state
            cur = (cur == 2) ? 0 : cur + 1;
        }
    }
#undef K2_BODY
}

extern "C" void kernel_launch(void* const* d_in, const int* in_sizes, int n_in,
                              void* d_out, int out_size, void* d_ws, size_t ws_size,
                              hipStream_t stream) {
    const float* x1    = (const float*)d_in[0];
    const float* x2    = (const float*)d_in[1];
    const float* W1    = (const float*)d_in[2];
    const float* b1    = (const float*)d_in[3];
    const float* W2    = (const float*)d_in[4];
    const float* b2    = (const float*)d_in[5];
    const float* Ws    = (const float*)d_in[6];
    const float* bs    = (const float*)d_in[7];
    const float* noise = (const float*)d_in[8];
    const float* rru   = (const float*)d_in[9];
    float* out = (float*)d_out;
    const int B = in_sizes[0] / FDIM;

    unsigned int* mmx = (unsigned int*)d_ws;
    __bf16* w1t = (__bf16*)((char*)d_ws + 256);                 // 160*128*2 = 40960 B
    __bf16* w2t = (__bf16*)((char*)d_ws + 256 + 40960);

    hipLaunchKernelGGL(k0_prep, dim3(64), dim3(256), 0, stream, W1, W2, mmx, w1t, w2t);
    hipLaunchKernelGGL(k1_sens, dim3(1024), dim3(256), 0, stream, x1, b1, w1t, mmx, B);
    hipLaunchKernelGGL(k2_main, dim3(512), dim3(256), 0, stream,
                       x1, x2, b1, b2, Ws, bs, noise, rru, w1t, w2t, mmx, out, B);
}